// Round 7
// baseline (259.193 us; speedup 1.0000x reference)
//
#include <hip/hip_runtime.h>
#include <hip/hip_bf16.h>

typedef unsigned short u16;
typedef __bf16 bf16_8 __attribute__((ext_vector_type(8)));
typedef float f32_4 __attribute__((ext_vector_type(4)));

#define IN_DIM 512
#define HID 64
#define OUT_DIM 40
#define CAP 64        // CSR slot capacity; deg~Poisson(16), P(deg>63)~0, guarded
#define CF_GRID 2048  // standalone countfill blocks

// ---- prep: zero cnt + transpose W1 fp32[512][64] -> W1t bf16[64][512] ----
__global__ void k_prep(const float* __restrict__ W1, u16* __restrict__ W1t,
                       int* __restrict__ cnt, int n) {
    int i = blockIdx.x * 256 + threadIdx.x;
    if (i < n) cnt[i] = 0;
    if (i < IN_DIM * HID) {
        int k = i / HID, o = i % HID;
        __hip_bfloat16 v = __float2bfloat16(W1[i]);
        W1t[o * IN_DIM + k] = *reinterpret_cast<u16*>(&v);
    }
}

// ---- standalone countfill: scatter edges into fixed-slot CSR ----
// Split out of k_work for per-kernel attribution (R7). ~1.5 edges/thread.
__launch_bounds__(256)
__global__ void k_cf(const int* __restrict__ src, const int* __restrict__ dst,
                     int* cnt, u16* __restrict__ csr, int E) {
    int e = blockIdx.x * 256 + threadIdx.x;
    const int stride = CF_GRID * 256;
    for (; e < E; e += stride) {
        int d = dst[e];
        int p = atomicAdd(&cnt[d], 1);
        if (p < CAP) csr[(size_t)d * CAP + p] = (u16)src[e];
    }
}

// ---- GEMM: hs(bf16) = X @ W1 (unscaled), 8-wave K-split blocks ----
// Journal of falsified k_work theories:
//  R1/R6: removing the LDS scaffold (dist-0 or named-reg dist-2 pipelines) -> 117/90us;
//         compiler collapses source register pipelines (VGPR fell to 40 both times).
//  R4:    BK=64 (half the barriers, 2x bytes per drain) -> neutral; barrier count and
//         bytes-in-flight per wave are not the limiter.
// R7: keep the EXACT R2 scaffold (BK=32, LDS double-buffer, 1 barrier/K-step, dist-1
// register prefetch) and change one variable: waves/CU. 512-thread blocks; waves 0-3
// compute k[0,256), waves 4-7 k[256,512); fp32 LDS reduction merges halves. Work per
// block unchanged, occupancy 12 -> 24 waves/CU (2x memory-level parallelism).
__launch_bounds__(512)
__global__ void k_gemm(const float* __restrict__ X, const u16* __restrict__ W1t,
                       u16* __restrict__ hs, int N) {
    __shared__ __align__(16) u16 As[2][2][64 * 40];   // [kgroup][buf][row*40+k]
    __shared__ __align__(16) float Red[64 * 64];      // group-1 partial sums
    const int t = threadIdx.x;
    const int g = t >> 8;            // k-group: 0 -> k[0,256), 1 -> k[256,512)
    const int wl = (t >> 6) & 3;     // wave within group
    const int lane = t & 63;
    const int m = lane & 15;
    const int quad = lane >> 4;
    const int n0 = blockIdx.x * 64;

    f32_4 acc[4];
    #pragma unroll
    for (int c = 0; c < 4; c++) acc[c] = (f32_4){0.f, 0.f, 0.f, 0.f};

    const int tg = t & 255;          // staging id within group
    const int r_st = tg >> 2;        // 0..63
    const int k_st = (tg & 3) * 8;   // 0,8,16,24

    int row = n0 + r_st; if (row >= N) row = N - 1;
    const float* xp = X + (size_t)row * IN_DIM + g * 256 + k_st;

    f32_4 x0 = *reinterpret_cast<const f32_4*>(xp);
    f32_4 x1 = *reinterpret_cast<const f32_4*>(xp + 4);

    int buf = 0;
    for (int ks = 0; ks < 256; ks += 32) {
        u16 xb[8];
        #pragma unroll
        for (int q = 0; q < 4; q++) {
            __hip_bfloat16 c0 = __float2bfloat16(x0[q]);
            __hip_bfloat16 c1 = __float2bfloat16(x1[q]);
            xb[q]     = *reinterpret_cast<u16*>(&c0);
            xb[4 + q] = *reinterpret_cast<u16*>(&c1);
        }
        *reinterpret_cast<uint4*>(&As[g][buf][r_st * 40 + k_st]) = *reinterpret_cast<uint4*>(xb);
        __syncthreads();

        if (ks + 32 < 256) {         // dist-1 register prefetch (R2-proven scaffold)
            x0 = *reinterpret_cast<const f32_4*>(xp + ks + 32);
            x1 = *reinterpret_cast<const f32_4*>(xp + ks + 36);
        }

        bf16_8 a = *reinterpret_cast<const bf16_8*>(&As[g][buf][(wl * 16 + m) * 40 + quad * 8]);
        #pragma unroll
        for (int c = 0; c < 4; c++) {    // B fragment from global W1t (64 KB, L2-hot)
            bf16_8 b = *reinterpret_cast<const bf16_8*>(
                W1t + (size_t)(c * 16 + m) * IN_DIM + g * 256 + ks + quad * 8);
            acc[c] = __builtin_amdgcn_mfma_f32_16x16x32_bf16(a, b, acc[c], 0, 0, 0);
        }
        buf ^= 1;
    }

    // merge k-halves: group 1 -> LDS, group 0 adds and stores.
    // C layout: col = c*16+m, local row = wl*16 + quad*4 + r.
    if (g == 1) {
        #pragma unroll
        for (int r = 0; r < 4; r++)
            #pragma unroll
            for (int c = 0; c < 4; c++)
                Red[(wl * 16 + quad * 4 + r) * 64 + c * 16 + m] = acc[c][r];
    }
    __syncthreads();
    if (g == 0) {
        const int nbase = n0 + wl * 16 + quad * 4;
        #pragma unroll
        for (int r = 0; r < 4; r++) {
            int n = nbase + r;
            if (n < N) {
                #pragma unroll
                for (int c = 0; c < 4; c++) {
                    float s = acc[c][r] + Red[(wl * 16 + quad * 4 + r) * 64 + c * 16 + m];
                    __hip_bfloat16 hv = __float2bfloat16(s);
                    hs[(size_t)n * HID + c * 16 + m] = *reinterpret_cast<u16*>(&hv);
                }
            }
        }
    }
}

// ---- scale pass: hs[n] = bf16(dinv[n] * hs[n]) in place (cnt is final now) ----
__global__ void k_scale(u16* __restrict__ hs, const int* __restrict__ cnt, int N) {
    int i = blockIdx.x * 256 + threadIdx.x;
    int node = i >> 3;
    if (node >= N) return;
    float dv = rsqrtf((float)cnt[node] + 1.0f);
    uint4 v = *reinterpret_cast<uint4*>(hs + (size_t)i * 8);
    uint vv[4] = {v.x, v.y, v.z, v.w};
    u16 o[8];
    #pragma unroll
    for (int q = 0; q < 4; q++) {
        float lo = __uint_as_float(vv[q] << 16) * dv;
        float hi = __uint_as_float(vv[q] & 0xFFFF0000u) * dv;
        __hip_bfloat16 bl_ = __float2bfloat16(lo);
        __hip_bfloat16 bh_ = __float2bfloat16(hi);
        o[2 * q]     = *reinterpret_cast<u16*>(&bl_);
        o[2 * q + 1] = *reinterpret_cast<u16*>(&bh_);
    }
    *reinterpret_cast<uint4*>(hs + (size_t)i * 8) = *reinterpret_cast<uint4*>(o);
}

// ---- fused agg + ReLU + FC(MFMA) ----
// hs rows are PRE-SCALED by dinv[s]; only the outer dinv[n] remains.
// CSR row loaded cooperatively (uint2 per lane), redistributed via __shfl;
// masked 16-deep gather rounds (R3: neutral vs 8-deep — gather latency not the pole).
__device__ __forceinline__ void acc_add(f32_4& a, uint2 v) {
    a[0] += __uint_as_float(v.x << 16);
    a[1] += __uint_as_float(v.x & 0xFFFF0000u);
    a[2] += __uint_as_float(v.y << 16);
    a[3] += __uint_as_float(v.y & 0xFFFF0000u);
}

#define SHP 72   // padded row pitch (bf16 elems): 144 B, conflict-free for b128 reads

__launch_bounds__(256)
__global__ void k_aggfc(const u16* __restrict__ hs, const u16* __restrict__ csr,
                        const int* __restrict__ cnt, const float* __restrict__ b1,
                        const float* __restrict__ Wfc, const float* __restrict__ bfc,
                        float* __restrict__ out, int N) {
    __shared__ __align__(16) u16 shb[16 * SHP];   // h2 rows, bf16, A-operand layout
    __shared__ __align__(16) u16 wfb[48 * SHP];   // Wfc^T padded: [o][k], rows 40..47 = 0
    __shared__ float bl[48];
    const int t = threadIdx.x;

    for (int i = t; i < 48 * HID; i += 256) {
        int o = i / HID, k = i % HID;
        float v = (o < OUT_DIM) ? Wfc[o * HID + k] : 0.f;
        __hip_bfloat16 b = __float2bfloat16(v);
        wfb[o * SHP + k] = *reinterpret_cast<u16*>(&b);
    }
    if (t < 48) bl[t] = (t < OUT_DIM) ? bfc[t] : 0.f;

    const int g = t >> 4, l = t & 15;
    const int n = blockIdx.x * 16 + g;

    if (n < N) {
        const uint2* hs2 = reinterpret_cast<const uint2*>(hs);
        f32_4 aa[4];
        #pragma unroll
        for (int q = 0; q < 4; q++) aa[q] = (f32_4){0.f, 0.f, 0.f, 0.f};
        const float dvn = rsqrtf((float)cnt[n] + 1.0f);
        acc_add(aa[0], hs2[(size_t)n * 16 + l]);         // self loop (pre-scaled)
        int deg = cnt[n]; if (deg > CAP) deg = CAP;
        // lane l holds CSR entries 4l..4l+3 of this node's row
        uint2 cv = reinterpret_cast<const uint2*>(csr + (size_t)n * CAP)[l];
        const int nn1 = N - 1;
        for (int j = 0; j < deg; j += 16) {
            int base = j >> 2;
            uint wx[4], wy[4];
            #pragma unroll
            for (int q = 0; q < 4; q++) {
                wx[q] = __shfl(cv.x, base + q, 16);
                wy[q] = __shfl(cv.y, base + q, 16);
            }
            int s[16];
            #pragma unroll
            for (int q = 0; q < 4; q++) {
                s[4 * q + 0] = (int)(wx[q] & 0xffff);
                s[4 * q + 1] = (int)(wx[q] >> 16);
                s[4 * q + 2] = (int)(wy[q] & 0xffff);
                s[4 * q + 3] = (int)(wy[q] >> 16);
            }
            uint2 v[16];
            #pragma unroll
            for (int i = 0; i < 16; i++) {
                int si = s[i] < nn1 ? s[i] : nn1;        // clamp (garbage-slot safety)
                v[i] = hs2[(size_t)si * 16 + l];
            }
            #pragma unroll
            for (int i = 0; i < 16; i++) {
                if (j + i >= deg) { v[i].x = 0u; v[i].y = 0u; }
                acc_add(aa[i & 3], v[i]);
            }
        }
        f32_4 acc = (aa[0] + aa[1]) + (aa[2] + aa[3]);
        u16 rb[4];
        #pragma unroll
        for (int q = 0; q < 4; q++) {
            float x = dvn * acc[q] + b1[l * 4 + q];
            x = x > 0.f ? x : 0.f;                       // ReLU
            __hip_bfloat16 hb = __float2bfloat16(x);
            rb[q] = *reinterpret_cast<u16*>(&hb);
        }
        *reinterpret_cast<uint2*>(&shb[g * SHP + l * 4]) = *reinterpret_cast<uint2*>(rb);
    }
    __syncthreads();

    // FC via MFMA: wave w handles o-tile w (w<3)
    const int wave = t >> 6;
    const int lane = t & 63;
    const int m = lane & 15;
    const int quad = lane >> 4;
    if (wave < 3) {
        bf16_8 a0 = *reinterpret_cast<const bf16_8*>(&shb[m * SHP + quad * 8]);
        bf16_8 a1 = *reinterpret_cast<const bf16_8*>(&shb[m * SHP + 32 + quad * 8]);
        bf16_8 b0 = *reinterpret_cast<const bf16_8*>(&wfb[(wave * 16 + m) * SHP + quad * 8]);
        bf16_8 b1 = *reinterpret_cast<const bf16_8*>(&wfb[(wave * 16 + m) * SHP + 32 + quad * 8]);
        f32_4 c = (f32_4){0.f, 0.f, 0.f, 0.f};
        c = __builtin_amdgcn_mfma_f32_16x16x32_bf16(a0, b0, c, 0, 0, 0);
        c = __builtin_amdgcn_mfma_f32_16x16x32_bf16(a1, b1, c, 0, 0, 0);
        const int o = wave * 16 + m;
        if (o < OUT_DIM) {
            const int base = blockIdx.x * 16;
            #pragma unroll
            for (int r = 0; r < 4; r++) {
                int node = base + quad * 4 + r;
                if (node < N) out[(size_t)node * OUT_DIM + o] = c[r] + bl[o];
            }
        }
    }
}

// ---------------- launch ----------------

extern "C" void kernel_launch(void* const* d_in, const int* in_sizes, int n_in,
                              void* d_out, int out_size, void* d_ws, size_t ws_size,
                              hipStream_t stream) {
    const float* X   = (const float*)d_in[0];
    const int* edges = (const int*)d_in[1];
    const float* W1  = (const float*)d_in[2];
    const float* b1  = (const float*)d_in[3];
    const float* Wfc = (const float*)d_in[4];
    const float* bfc = (const float*)d_in[5];

    const int N = in_sizes[0] / IN_DIM;
    const int E = in_sizes[1] / 2;
    const int* src = edges;
    const int* dst = edges + E;

    char* p = (char*)d_ws;
    auto carve = [&](size_t bytes) -> char* {
        char* r = p;
        p += (bytes + 255) & ~(size_t)255;
        return r;
    };
    u16* W1t = (u16*)carve((size_t)IN_DIM * HID * 2);
    u16* hs  = (u16*)carve((size_t)N * HID * 2);
    int* cnt = (int*)carve((size_t)N * 4);
    u16* csr = (u16*)carve((size_t)N * CAP * 2);

    const int nb = (N + 255) / 256;
    const int NT = (N + 63) / 64;

    k_prep <<<nb, 256, 0, stream>>>(W1, W1t, cnt, N);
    k_cf   <<<CF_GRID, 256, 0, stream>>>(src, dst, cnt, csr, E);
    k_gemm <<<NT, 512, 0, stream>>>(X, W1t, hs, N);
    k_scale<<<(N * 8 + 255) / 256, 256, 0, stream>>>(hs, cnt, N);
    k_aggfc<<<(N + 15) / 16, 256, 0, stream>>>(hs, csr, cnt, b1, Wfc, bfc,
                                               (float*)d_out, N);
}

// Round 8
// 241.193 us; speedup vs baseline: 1.0746x; 1.0746x over previous
//
#include <hip/hip_runtime.h>
#include <hip/hip_bf16.h>

typedef unsigned short u16;
typedef __bf16 bf16_8 __attribute__((ext_vector_type(8)));
typedef float f32_4 __attribute__((ext_vector_type(4)));

#define IN_DIM 512
#define HID 64
#define OUT_DIM 40
#define CAP 64       // CSR slot capacity; deg~Poisson(16), P(deg>63)~0, guarded
#define CF_BLK 256   // countfill blocks, placed at the FRONT of the grid

// ---- prep: zero cnt + transpose W1 fp32[512][64] -> W1t bf16[64][512] ----
__global__ void k_prep(const float* __restrict__ W1, u16* __restrict__ W1t,
                       int* __restrict__ cnt, int n) {
    int i = blockIdx.x * 256 + threadIdx.x;
    if (i < n) cnt[i] = 0;
    if (i < IN_DIM * HID) {
        int k = i / HID, o = i % HID;
        __hip_bfloat16 v = __float2bfloat16(W1[i]);
        W1t[o * IN_DIM + k] = *reinterpret_cast<u16*>(&v);
    }
}

// ---- fused work: blocks [0,CF_BLK) = countfill; [CF_BLK, CF_BLK+NT) = GEMM tiles ----
// R7 attribution (split kernels): k_cf standalone = 60us (WRITE 44.5MB = 50k nodes x 2
// sectors x 64B x 8 XCDs of mandatory non-coherent-L2 writeback, ~740 GB/s random-sector;
// VALUBusy 0.45% — pure scatter). k_gemm (8-wave K-split) ~= 48us — the occupancy lever
// (12 -> 24 waves/CU) is what finally beat the 80us GEMM; barriers/bytes-in-flight were
// falsified in R1/R4/R6. This round re-fuses them so the scatter (write-dominant) hides
// under the GEMM (read-dominant). CF blocks go FIRST: grid (1038 blocks) exceeds the
// ~4 blocks/CU residency, so tail-placed CF would queue behind GEMM instead of overlapping.
__launch_bounds__(512)
__global__ void k_work(const float* __restrict__ X, const u16* __restrict__ W1t,
                       const int* __restrict__ src, const int* __restrict__ dst,
                       int* cnt, u16* __restrict__ csr, u16* __restrict__ hs,
                       int N, int E) {
    __shared__ __align__(16) u16 As[2][2][64 * 40];   // [kgroup][buf][row*40+k]
    __shared__ __align__(16) float Red[64 * 64];      // group-1 partial sums
    const int t = threadIdx.x;

    if ((int)blockIdx.x < CF_BLK) {
        // ---------------- countfill partition ----------------
        int e = (int)blockIdx.x * 512 + t;
        const int stride = CF_BLK * 512;
        for (; e + stride < E; e += 2 * stride) {
            int d0 = dst[e], d1 = dst[e + stride];
            int s0 = src[e], s1 = src[e + stride];
            int p0 = atomicAdd(&cnt[d0], 1);
            int p1 = atomicAdd(&cnt[d1], 1);
            if (p0 < CAP) csr[(size_t)d0 * CAP + p0] = (u16)s0;
            if (p1 < CAP) csr[(size_t)d1 * CAP + p1] = (u16)s1;
        }
        for (; e < E; e += stride) {
            int d = dst[e];
            int p = atomicAdd(&cnt[d], 1);
            if (p < CAP) csr[(size_t)d * CAP + p] = (u16)src[e];
        }
        return;
    }

    // ---------------- GEMM tile: hs(bf16) = X @ W1 (unscaled), 8-wave K-split ----------------
    // waves 0-3 (g=0) compute k[0,256), waves 4-7 (g=1) k[256,512); LDS merge at end.
    const int g = t >> 8;
    const int wl = (t >> 6) & 3;
    const int lane = t & 63;
    const int m = lane & 15;
    const int quad = lane >> 4;
    const int n0 = ((int)blockIdx.x - CF_BLK) * 64;

    f32_4 acc[4];
    #pragma unroll
    for (int c = 0; c < 4; c++) acc[c] = (f32_4){0.f, 0.f, 0.f, 0.f};

    const int tg = t & 255;          // staging id within group
    const int r_st = tg >> 2;        // 0..63
    const int k_st = (tg & 3) * 8;   // 0,8,16,24

    int row = n0 + r_st; if (row >= N) row = N - 1;
    const float* xp = X + (size_t)row * IN_DIM + g * 256 + k_st;

    f32_4 x0 = *reinterpret_cast<const f32_4*>(xp);
    f32_4 x1 = *reinterpret_cast<const f32_4*>(xp + 4);

    int buf = 0;
    for (int ks = 0; ks < 256; ks += 32) {
        u16 xb[8];
        #pragma unroll
        for (int q = 0; q < 4; q++) {
            __hip_bfloat16 c0 = __float2bfloat16(x0[q]);
            __hip_bfloat16 c1 = __float2bfloat16(x1[q]);
            xb[q]     = *reinterpret_cast<u16*>(&c0);
            xb[4 + q] = *reinterpret_cast<u16*>(&c1);
        }
        *reinterpret_cast<uint4*>(&As[g][buf][r_st * 40 + k_st]) = *reinterpret_cast<uint4*>(xb);
        __syncthreads();

        if (ks + 32 < 256) {         // dist-1 register prefetch (R2-proven scaffold)
            x0 = *reinterpret_cast<const f32_4*>(xp + ks + 32);
            x1 = *reinterpret_cast<const f32_4*>(xp + ks + 36);
        }

        bf16_8 a = *reinterpret_cast<const bf16_8*>(&As[g][buf][(wl * 16 + m) * 40 + quad * 8]);
        #pragma unroll
        for (int c = 0; c < 4; c++) {    // B fragment from global W1t (64 KB, L2-hot)
            bf16_8 b = *reinterpret_cast<const bf16_8*>(
                W1t + (size_t)(c * 16 + m) * IN_DIM + g * 256 + ks + quad * 8);
            acc[c] = __builtin_amdgcn_mfma_f32_16x16x32_bf16(a, b, acc[c], 0, 0, 0);
        }
        buf ^= 1;
    }

    // merge k-halves: group 1 -> LDS, group 0 adds and stores.
    // C layout: col = c*16+m, local row = wl*16 + quad*4 + r.
    if (g == 1) {
        #pragma unroll
        for (int r = 0; r < 4; r++)
            #pragma unroll
            for (int c = 0; c < 4; c++)
                Red[(wl * 16 + quad * 4 + r) * 64 + c * 16 + m] = acc[c][r];
    }
    __syncthreads();
    if (g == 0) {
        const int nbase = n0 + wl * 16 + quad * 4;
        #pragma unroll
        for (int r = 0; r < 4; r++) {
            int n = nbase + r;
            if (n < N) {
                #pragma unroll
                for (int c = 0; c < 4; c++) {
                    float s = acc[c][r] + Red[(wl * 16 + quad * 4 + r) * 64 + c * 16 + m];
                    __hip_bfloat16 hv = __float2bfloat16(s);
                    hs[(size_t)n * HID + c * 16 + m] = *reinterpret_cast<u16*>(&hv);
                }
            }
        }
    }
}

// ---- scale pass: hs[n] = bf16(dinv[n] * hs[n]) in place (cnt is final now) ----
__global__ void k_scale(u16* __restrict__ hs, const int* __restrict__ cnt, int N) {
    int i = blockIdx.x * 256 + threadIdx.x;
    int node = i >> 3;
    if (node >= N) return;
    float dv = rsqrtf((float)cnt[node] + 1.0f);
    uint4 v = *reinterpret_cast<uint4*>(hs + (size_t)i * 8);
    uint vv[4] = {v.x, v.y, v.z, v.w};
    u16 o[8];
    #pragma unroll
    for (int q = 0; q < 4; q++) {
        float lo = __uint_as_float(vv[q] << 16) * dv;
        float hi = __uint_as_float(vv[q] & 0xFFFF0000u) * dv;
        __hip_bfloat16 bl_ = __float2bfloat16(lo);
        __hip_bfloat16 bh_ = __float2bfloat16(hi);
        o[2 * q]     = *reinterpret_cast<u16*>(&bl_);
        o[2 * q + 1] = *reinterpret_cast<u16*>(&bh_);
    }
    *reinterpret_cast<uint4*>(hs + (size_t)i * 8) = *reinterpret_cast<uint4*>(o);
}

// ---- fused agg + ReLU + FC(MFMA) ----
// hs rows are PRE-SCALED by dinv[s]; only the outer dinv[n] remains.
// CSR row loaded cooperatively (uint2 per lane), redistributed via __shfl;
// masked 16-deep gather rounds (R3: neutral vs 8-deep — gather latency not the pole).
__device__ __forceinline__ void acc_add(f32_4& a, uint2 v) {
    a[0] += __uint_as_float(v.x << 16);
    a[1] += __uint_as_float(v.x & 0xFFFF0000u);
    a[2] += __uint_as_float(v.y << 16);
    a[3] += __uint_as_float(v.y & 0xFFFF0000u);
}

#define SHP 72   // padded row pitch (bf16 elems): 144 B, conflict-free for b128 reads

__launch_bounds__(256)
__global__ void k_aggfc(const u16* __restrict__ hs, const u16* __restrict__ csr,
                        const int* __restrict__ cnt, const float* __restrict__ b1,
                        const float* __restrict__ Wfc, const float* __restrict__ bfc,
                        float* __restrict__ out, int N) {
    __shared__ __align__(16) u16 shb[16 * SHP];   // h2 rows, bf16, A-operand layout
    __shared__ __align__(16) u16 wfb[48 * SHP];   // Wfc^T padded: [o][k], rows 40..47 = 0
    __shared__ float bl[48];
    const int t = threadIdx.x;

    for (int i = t; i < 48 * HID; i += 256) {
        int o = i / HID, k = i % HID;
        float v = (o < OUT_DIM) ? Wfc[o * HID + k] : 0.f;
        __hip_bfloat16 b = __float2bfloat16(v);
        wfb[o * SHP + k] = *reinterpret_cast<u16*>(&b);
    }
    if (t < 48) bl[t] = (t < OUT_DIM) ? bfc[t] : 0.f;

    const int g = t >> 4, l = t & 15;
    const int n = blockIdx.x * 16 + g;

    if (n < N) {
        const uint2* hs2 = reinterpret_cast<const uint2*>(hs);
        f32_4 aa[4];
        #pragma unroll
        for (int q = 0; q < 4; q++) aa[q] = (f32_4){0.f, 0.f, 0.f, 0.f};
        const float dvn = rsqrtf((float)cnt[n] + 1.0f);
        acc_add(aa[0], hs2[(size_t)n * 16 + l]);         // self loop (pre-scaled)
        int deg = cnt[n]; if (deg > CAP) deg = CAP;
        // lane l holds CSR entries 4l..4l+3 of this node's row
        uint2 cv = reinterpret_cast<const uint2*>(csr + (size_t)n * CAP)[l];
        const int nn1 = N - 1;
        for (int j = 0; j < deg; j += 16) {
            int base = j >> 2;
            uint wx[4], wy[4];
            #pragma unroll
            for (int q = 0; q < 4; q++) {
                wx[q] = __shfl(cv.x, base + q, 16);
                wy[q] = __shfl(cv.y, base + q, 16);
            }
            int s[16];
            #pragma unroll
            for (int q = 0; q < 4; q++) {
                s[4 * q + 0] = (int)(wx[q] & 0xffff);
                s[4 * q + 1] = (int)(wx[q] >> 16);
                s[4 * q + 2] = (int)(wy[q] & 0xffff);
                s[4 * q + 3] = (int)(wy[q] >> 16);
            }
            uint2 v[16];
            #pragma unroll
            for (int i = 0; i < 16; i++) {
                int si = s[i] < nn1 ? s[i] : nn1;        // clamp (garbage-slot safety)
                v[i] = hs2[(size_t)si * 16 + l];
            }
            #pragma unroll
            for (int i = 0; i < 16; i++) {
                if (j + i >= deg) { v[i].x = 0u; v[i].y = 0u; }
                acc_add(aa[i & 3], v[i]);
            }
        }
        f32_4 acc = (aa[0] + aa[1]) + (aa[2] + aa[3]);
        u16 rb[4];
        #pragma unroll
        for (int q = 0; q < 4; q++) {
            float x = dvn * acc[q] + b1[l * 4 + q];
            x = x > 0.f ? x : 0.f;                       // ReLU
            __hip_bfloat16 hb = __float2bfloat16(x);
            rb[q] = *reinterpret_cast<u16*>(&hb);
        }
        *reinterpret_cast<uint2*>(&shb[g * SHP + l * 4]) = *reinterpret_cast<uint2*>(rb);
    }
    __syncthreads();

    // FC via MFMA: wave w handles o-tile w (w<3)
    const int wave = t >> 6;
    const int lane = t & 63;
    const int m = lane & 15;
    const int quad = lane >> 4;
    if (wave < 3) {
        bf16_8 a0 = *reinterpret_cast<const bf16_8*>(&shb[m * SHP + quad * 8]);
        bf16_8 a1 = *reinterpret_cast<const bf16_8*>(&shb[m * SHP + 32 + quad * 8]);
        bf16_8 b0 = *reinterpret_cast<const bf16_8*>(&wfb[(wave * 16 + m) * SHP + quad * 8]);
        bf16_8 b1 = *reinterpret_cast<const bf16_8*>(&wfb[(wave * 16 + m) * SHP + 32 + quad * 8]);
        f32_4 c = (f32_4){0.f, 0.f, 0.f, 0.f};
        c = __builtin_amdgcn_mfma_f32_16x16x32_bf16(a0, b0, c, 0, 0, 0);
        c = __builtin_amdgcn_mfma_f32_16x16x32_bf16(a1, b1, c, 0, 0, 0);
        const int o = wave * 16 + m;
        if (o < OUT_DIM) {
            const int base = blockIdx.x * 16;
            #pragma unroll
            for (int r = 0; r < 4; r++) {
                int node = base + quad * 4 + r;
                if (node < N) out[(size_t)node * OUT_DIM + o] = c[r] + bl[o];
            }
        }
    }
}

// ---------------- launch ----------------

extern "C" void kernel_launch(void* const* d_in, const int* in_sizes, int n_in,
                              void* d_out, int out_size, void* d_ws, size_t ws_size,
                              hipStream_t stream) {
    const float* X   = (const float*)d_in[0];
    const int* edges = (const int*)d_in[1];
    const float* W1  = (const float*)d_in[2];
    const float* b1  = (const float*)d_in[3];
    const float* Wfc = (const float*)d_in[4];
    const float* bfc = (const float*)d_in[5];

    const int N = in_sizes[0] / IN_DIM;
    const int E = in_sizes[1] / 2;
    const int* src = edges;
    const int* dst = edges + E;

    char* p = (char*)d_ws;
    auto carve = [&](size_t bytes) -> char* {
        char* r = p;
        p += (bytes + 255) & ~(size_t)255;
        return r;
    };
    u16* W1t = (u16*)carve((size_t)IN_DIM * HID * 2);
    u16* hs  = (u16*)carve((size_t)N * HID * 2);
    int* cnt = (int*)carve((size_t)N * 4);
    u16* csr = (u16*)carve((size_t)N * CAP * 2);

    const int nb = (N + 255) / 256;
    const int NT = (N + 63) / 64;

    k_prep <<<nb, 256, 0, stream>>>(W1, W1t, cnt, N);
    k_work <<<CF_BLK + NT, 512, 0, stream>>>(X, W1t, src, dst, cnt, csr, hs, N, E);
    k_scale<<<(N * 8 + 255) / 256, 256, 0, stream>>>(hs, cnt, N);
    k_aggfc<<<(N + 15) / 16, 256, 0, stream>>>(hs, csr, cnt, b1, Wfc, bfc,
                                               (float*)d_out, N);
}